// Round 6
// baseline (384.608 us; speedup 1.0000x reference)
//
#include <hip/hip_runtime.h>
#include <hip/hip_bf16.h>

// ---------------------------------------------------------------------------
// DyadXLSTM forward. fp32 in/out; bf16 activations into MFMA GEMMs.
// mLSTM recurrence = chunked causal decay-attention (exact rewrite).
// sLSTM sequential scan: register-resident R (pre-transposed), readlane
// broadcast, raw s_barrier (no vmcnt drain) per step.
// B=32 T=256 NH=4 DH=64 D=H=256, BT=8192.
// ---------------------------------------------------------------------------

#define BT 8192
#define SZ ((size_t)BT * 256)

typedef __attribute__((ext_vector_type(4))) float  f32x4;
typedef __attribute__((ext_vector_type(8))) short  s16x8;

__device__ __forceinline__ float bf2f(unsigned short u) {
    return __uint_as_float(((unsigned int)u) << 16);
}
__device__ __forceinline__ unsigned short f2bf(float f) {
    __hip_bfloat16 h = __float2bfloat16(f);
    return *(unsigned short*)&h;
}
__device__ __forceinline__ float rdlane(float v, int l) {
    return __int_as_float(__builtin_amdgcn_readlane(__float_as_int(v), l));
}

// ---------------------------------------------------------------------------
// Convert+transpose 15 weight matrices (256x256 fp32 K-major) -> bf16 Wt[slot][N][K]
__global__ __launch_bounds__(256) void conv_w(
    const float* mWq, const float* mWk, const float* mWv, const float* mWo,
    const float* mWp, const float* sWz, const float* sWi, const float* sWf,
    const float* sWo, const float* sWp, unsigned short* __restrict__ Wt)
{
    int z = blockIdx.z;
    const float* mp[5] = {mWq, mWk, mWv, mWo, mWp};
    const float* sp[5] = {sWz, sWi, sWf, sWo, sWp};
    const float* src;
    if (z < 5)       src = mp[z];
    else if (z < 10) src = sp[z - 5];
    else             src = mp[z - 10] + 65536;
    int kB = blockIdx.x * 64, nB = blockIdx.y * 64;
    __shared__ unsigned short Ts[64][68];
    int tid = threadIdx.x;
    int r = tid >> 2, c = (tid & 3) * 16;
    #pragma unroll
    for (int j = 0; j < 16; j += 4) {
        float4 wv = *(const float4*)(src + (size_t)(kB + r) * 256 + nB + c + j);
        Ts[r][c + j]     = f2bf(wv.x); Ts[r][c + j + 1] = f2bf(wv.y);
        Ts[r][c + j + 2] = f2bf(wv.z); Ts[r][c + j + 3] = f2bf(wv.w);
    }
    __syncthreads();
    int n = tid >> 2, k0 = (tid & 3) * 16;
    __attribute__((aligned(16))) unsigned short tmp[16];
    #pragma unroll
    for (int j = 0; j < 16; ++j) tmp[j] = Ts[k0 + j][n];
    unsigned short* dst = Wt + (size_t)z * 65536 + (size_t)(nB + n) * 256 + kB + k0;
    *(uint4*)dst       = *(const uint4*)tmp;
    *(uint4*)(dst + 8) = *(const uint4*)(tmp + 8);
}

// ---------------------------------------------------------------------------
// Transpose sLSTM recurrent mats: Rt[gate][h][e][d] = R_gate[h][d][e]
__global__ __launch_bounds__(256) void transp_r(
    const float* __restrict__ Rz, const float* __restrict__ Ri,
    const float* __restrict__ Rf, const float* __restrict__ Ro,
    float* __restrict__ Rt)
{
    int g = blockIdx.x >> 2, h = blockIdx.x & 3;
    const float* R = (g == 0 ? Rz : g == 1 ? Ri : g == 2 ? Rf : Ro) + h * 4096;
    __shared__ float Ts[64][65];
    int tid = threadIdx.x;
    int d = tid >> 2, c4 = (tid & 3) * 16;
    #pragma unroll
    for (int j = 0; j < 16; j += 4)
        *(float4*)&Ts[d][c4 + j] = *(const float4*)(R + d * 64 + c4 + j);
    __syncthreads();
    int e = tid >> 2;
    #pragma unroll
    for (int j = 0; j < 16; j += 4) {
        float4 v = make_float4(Ts[c4 + j][e], Ts[c4 + j + 1][e],
                               Ts[c4 + j + 2][e], Ts[c4 + j + 3][e]);
        *(float4*)(Rt + (((size_t)g * 4 + h) * 64 + e) * 64 + c4 + j) = v;
    }
}

// ---------------------------------------------------------------------------
__global__ __launch_bounds__(256) void build_x(
    const float* __restrict__ X, const int* __restrict__ dyad,
    const float* __restrict__ embed, float* __restrict__ x)
{
    int i = blockIdx.x * 256 + threadIdx.x;
    int d = i & 255, bt = i >> 8, b = bt >> 8;
    x[i] = (d < 224) ? X[bt * 224 + d] : embed[dyad[b] * 32 + (d - 224)];
}

// ---------------------------------------------------------------------------
// LayerNorm: one WAVE per row, 4 elems/lane, no LDS, no barriers.
__global__ __launch_bounds__(256) void layernorm(
    const float* __restrict__ x, const float* __restrict__ g,
    const float* __restrict__ b, unsigned short* __restrict__ xn)
{
    int row = blockIdx.x * 4 + (threadIdx.x >> 6);
    int lane = threadIdx.x & 63;
    float4 v = *(const float4*)(x + (size_t)row * 256 + lane * 4);
    float s  = v.x + v.y + v.z + v.w;
    float s2 = v.x * v.x + v.y * v.y + v.z * v.z + v.w * v.w;
    #pragma unroll
    for (int o = 32; o; o >>= 1) { s += __shfl_xor(s, o); s2 += __shfl_xor(s2, o); }
    float mu  = s * (1.f / 256.f);
    float var = s2 * (1.f / 256.f) - mu * mu;
    float inv = rsqrtf(var + 1e-5f);
    float4 gv = *(const float4*)(g + lane * 4);
    float4 bv = *(const float4*)(b + lane * 4);
    ushort4 o4;
    o4.x = f2bf((v.x - mu) * inv * gv.x + bv.x);
    o4.y = f2bf((v.y - mu) * inv * gv.y + bv.y);
    o4.z = f2bf((v.z - mu) * inv * gv.z + bv.z);
    o4.w = f2bf((v.w - mu) * inv * gv.w + bv.w);
    *(ushort4*)(xn + (size_t)row * 256 + lane * 4) = o4;
}

// ---------------------------------------------------------------------------
// bf16-out GEMM: out[z][8192][256](bf16) = alpha_z * A(bf16) @ Wt[slot0+z]^T
__global__ __launch_bounds__(256) void gemm_mfma_bf16(
    const unsigned short* __restrict__ A, const unsigned short* __restrict__ Wt,
    int slot0, unsigned short* out0, float a0, float a1, float a2, float a3)
{
    __shared__ unsigned short As[64 * 40];
    __shared__ unsigned short Bs[64 * 40];
    int tid = threadIdx.x, bz = blockIdx.z;
    const unsigned short* W = Wt + (size_t)(slot0 + bz) * 65536;
    unsigned short* out = out0 + (size_t)bz * SZ;
    float alpha = bz == 0 ? a0 : bz == 1 ? a1 : bz == 2 ? a2 : a3;
    int rowBase = blockIdx.x * 64, colBase = blockIdx.y * 64;
    int srow = tid >> 2, scol = (tid & 3) * 8;
    const unsigned short* Ap = A + (size_t)(rowBase + srow) * 256 + scol;
    const unsigned short* Wp = W + (size_t)(colBase + srow) * 256 + scol;
    unsigned short* Asw = As + srow * 40 + scol;
    unsigned short* Bsw = Bs + srow * 40 + scol;
    int w = tid >> 6, lane = tid & 63, quad = lane >> 4, l15 = lane & 15;
    const unsigned short* Ar  = As + (w * 16 + l15) * 40 + quad * 8;
    const unsigned short* Br0 = Bs + l15 * 40 + quad * 8;
    f32x4 acc[4];
    #pragma unroll
    for (int c = 0; c < 4; ++c) acc[c] = (f32x4){0.f, 0.f, 0.f, 0.f};
    for (int k0 = 0; k0 < 256; k0 += 32) {
        uint4 av = *(const uint4*)(Ap + k0);
        uint4 bv = *(const uint4*)(Wp + k0);
        __syncthreads();
        *(uint4*)Asw = av;
        *(uint4*)Bsw = bv;
        __syncthreads();
        s16x8 af = *(const s16x8*)Ar;
        #pragma unroll
        for (int c = 0; c < 4; ++c) {
            s16x8 bf = *(const s16x8*)(Br0 + c * 16 * 40);
            acc[c] = __builtin_amdgcn_mfma_f32_16x16x32_bf16(af, bf, acc[c], 0, 0, 0);
        }
    }
    #pragma unroll
    for (int c = 0; c < 4; ++c) {
        int col  = colBase + c * 16 + l15;
        int row0 = rowBase + w * 16 + quad * 4;
        #pragma unroll
        for (int i2 = 0; i2 < 4; ++i2)
            out[(size_t)(row0 + i2) * 256 + col] = f2bf(alpha * acc[c][i2]);
    }
}

// ---------------------------------------------------------------------------
// fp32-out GEMM with residual: out = A(bf16) @ Wt[slot]^T + Res
__global__ __launch_bounds__(256) void gemm_mfma_f32(
    const unsigned short* __restrict__ A, const unsigned short* __restrict__ Wt,
    int slot, float* __restrict__ out, const float* __restrict__ Res)
{
    __shared__ unsigned short As[64 * 40];
    __shared__ unsigned short Bs[64 * 40];
    int tid = threadIdx.x;
    const unsigned short* W = Wt + (size_t)slot * 65536;
    int rowBase = blockIdx.x * 64, colBase = blockIdx.y * 64;
    int srow = tid >> 2, scol = (tid & 3) * 8;
    const unsigned short* Ap = A + (size_t)(rowBase + srow) * 256 + scol;
    const unsigned short* Wp = W + (size_t)(colBase + srow) * 256 + scol;
    unsigned short* Asw = As + srow * 40 + scol;
    unsigned short* Bsw = Bs + srow * 40 + scol;
    int w = tid >> 6, lane = tid & 63, quad = lane >> 4, l15 = lane & 15;
    const unsigned short* Ar  = As + (w * 16 + l15) * 40 + quad * 8;
    const unsigned short* Br0 = Bs + l15 * 40 + quad * 8;
    f32x4 acc[4];
    #pragma unroll
    for (int c = 0; c < 4; ++c) acc[c] = (f32x4){0.f, 0.f, 0.f, 0.f};
    for (int k0 = 0; k0 < 256; k0 += 32) {
        uint4 av = *(const uint4*)(Ap + k0);
        uint4 bv = *(const uint4*)(Wp + k0);
        __syncthreads();
        *(uint4*)Asw = av;
        *(uint4*)Bsw = bv;
        __syncthreads();
        s16x8 af = *(const s16x8*)Ar;
        #pragma unroll
        for (int c = 0; c < 4; ++c) {
            s16x8 bf = *(const s16x8*)(Br0 + c * 16 * 40);
            acc[c] = __builtin_amdgcn_mfma_f32_16x16x32_bf16(af, bf, acc[c], 0, 0, 0);
        }
    }
    #pragma unroll
    for (int c = 0; c < 4; ++c) {
        int col  = colBase + c * 16 + l15;
        int row0 = rowBase + w * 16 + quad * 4;
        #pragma unroll
        for (int i2 = 0; i2 < 4; ++i2) {
            size_t idx = (size_t)(row0 + i2) * 256 + col;
            out[idx] = acc[c][i2] + Res[idx];
        }
    }
}

// ---------------------------------------------------------------------------
// gi/gf[row,h] = xn[row,:].W{i,f}[:,h] + b{i,f}[h]
__global__ __launch_bounds__(256) void gate_gemm(
    const unsigned short* __restrict__ xn,
    const float* __restrict__ Wi, const float* __restrict__ Wf,
    const float* __restrict__ bi, const float* __restrict__ bf_,
    float* __restrict__ gi, float* __restrict__ gf)
{
    int tid = threadIdx.x;
    int hh = tid & 3;
    int row = blockIdx.x * 64 + (tid >> 2);
    float ai = bi[hh], af = bf_[hh];
    const unsigned short* xr = xn + (size_t)row * 256;
    for (int k2 = 0; k2 < 256; ++k2) {
        float xv = bf2f(xr[k2]);
        ai += xv * Wi[k2 * 4 + hh];
        af += xv * Wf[k2 * 4 + hh];
    }
    gi[row * 4 + hh] = ai;
    gf[row * 4 + hh] = af;
}

// ---------------------------------------------------------------------------
// Per-(b,h): F = cumsum(fp); a = ip - F; M = max(0, prefix-max(a)).
__global__ __launch_bounds__(256) void scan_am(
    const float* __restrict__ gi, const float* __restrict__ gf,
    float* __restrict__ a_arr, float* __restrict__ M_arr)
{
    int bh = blockIdx.x, b = bh >> 2, h = bh & 3;
    int t = threadIdx.x;
    float fp = gf[(b * 256 + t) * 4 + h];
    float ip = gi[(b * 256 + t) * 4 + h];
    __shared__ float buf[256];
    buf[t] = fp;
    __syncthreads();
    #pragma unroll
    for (int o = 1; o < 256; o <<= 1) {
        float add = (t >= o) ? buf[t - o] : 0.f;
        __syncthreads();
        buf[t] += add;
        __syncthreads();
    }
    float F = buf[t];
    float a = ip - F;
    __syncthreads();
    buf[t] = a;
    __syncthreads();
    #pragma unroll
    for (int o = 1; o < 256; o <<= 1) {
        float mx = (t >= o) ? buf[t - o] : -3.4e38f;
        __syncthreads();
        buf[t] = fmaxf(buf[t], mx);
        __syncthreads();
    }
    a_arr[bh * 256 + t] = a;
    M_arr[bh * 256 + t] = fmaxf(buf[t], 0.f);
}

// ---------------------------------------------------------------------------
// mLSTM as causal decay-attention. Block = (bh, row-tile rt of 64).
__global__ __launch_bounds__(256) void mlstm_attn(
    const unsigned short* __restrict__ qb, const unsigned short* __restrict__ kb,
    const unsigned short* __restrict__ vb, const unsigned short* __restrict__ ob,
    const float* __restrict__ a_arr, const float* __restrict__ M_arr,
    unsigned short* __restrict__ hout)
{
    int bh = blockIdx.x, rt = blockIdx.y;
    int b = bh >> 2, h = bh & 3;
    int tid = threadIdx.x, w = tid >> 6, lane = tid & 63;
    int quad = lane >> 4, l15 = lane & 15;
    __shared__ unsigned short Qs[64][72];
    __shared__ unsigned short Ks[64][72];
    __shared__ unsigned short Vt[64][72];
    __shared__ unsigned short Ps[4][16][72];
    __shared__ float a_s[64], M_s[64];
    int sr = tid >> 2, sc = (tid & 3) * 16;
    size_t qoff = (size_t)(b * 256 + rt * 64 + sr) * 256 + h * 64 + sc;
    *(uint4*)&Qs[sr][sc]     = *(const uint4*)(qb + qoff);
    *(uint4*)&Qs[sr][sc + 8] = *(const uint4*)(qb + qoff + 8);
    if (tid < 64) M_s[tid] = M_arr[bh * 256 + rt * 64 + tid];
    f32x4 accN[4];
    #pragma unroll
    for (int c = 0; c < 4; ++c) accN[c] = (f32x4){0.f, 0.f, 0.f, 0.f};
    f32x4 den = (f32x4){0.f, 0.f, 0.f, 0.f};
    int rowT = w * 16 + quad * 4;
    for (int ct = 0; ct <= rt; ++ct) {
        size_t koff = (size_t)(b * 256 + ct * 64 + sr) * 256 + h * 64 + sc;
        uint4 kv0 = *(const uint4*)(kb + koff);
        uint4 kv1 = *(const uint4*)(kb + koff + 8);
        uint4 vv0 = *(const uint4*)(vb + koff);
        uint4 vv1 = *(const uint4*)(vb + koff + 8);
        *(uint4*)&Ks[sr][sc]     = kv0;
        *(uint4*)&Ks[sr][sc + 8] = kv1;
        __attribute__((aligned(16))) unsigned short vt[16];
        *(uint4*)vt = vv0; *(uint4*)(vt + 8) = vv1;
        #pragma unroll
        for (int jj = 0; jj < 16; ++jj) Vt[sc + jj][sr] = vt[jj];
        if (tid < 64) a_s[tid] = a_arr[bh * 256 + ct * 64 + tid];
        __syncthreads();
        f32x4 S[4];
        #pragma unroll
        for (int c = 0; c < 4; ++c) S[c] = (f32x4){0.f, 0.f, 0.f, 0.f};
        #pragma unroll
        for (int ks = 0; ks < 2; ++ks) {
            s16x8 af = *(const s16x8*)&Qs[w * 16 + l15][quad * 8 + ks * 32];
            #pragma unroll
            for (int c = 0; c < 4; ++c) {
                s16x8 bfr = *(const s16x8*)&Ks[c * 16 + l15][quad * 8 + ks * 32];
                S[c] = __builtin_amdgcn_mfma_f32_16x16x32_bf16(af, bfr, S[c], 0, 0, 0);
            }
        }
        bool dg = (ct == rt);
        #pragma unroll
        for (int c = 0; c < 4; ++c) {
            int col = c * 16 + l15;
            #pragma unroll
            for (int i2 = 0; i2 < 4; ++i2) {
                int row = rowT + i2;
                float p = S[c][i2] * __expf(a_s[col] - M_s[row]);
                if (dg && col > row) p = 0.f;
                S[c][i2] = p;
                den[i2] += p;
            }
        }
        #pragma unroll
        for (int c = 0; c < 4; ++c)
            #pragma unroll
            for (int i2 = 0; i2 < 4; ++i2)
                Ps[w][quad * 4 + i2][c * 16 + l15] = f2bf(S[c][i2]);
        __syncthreads();
        #pragma unroll
        for (int ks = 0; ks < 2; ++ks) {
            s16x8 af = *(const s16x8*)&Ps[w][l15][quad * 8 + ks * 32];
            #pragma unroll
            for (int c = 0; c < 4; ++c) {
                s16x8 bfr = *(const s16x8*)&Vt[c * 16 + l15][quad * 8 + ks * 32];
                accN[c] = __builtin_amdgcn_mfma_f32_16x16x32_bf16(af, bfr, accN[c], 0, 0, 0);
            }
        }
        __syncthreads();
    }
    #pragma unroll
    for (int ofs = 1; ofs < 16; ofs <<= 1) {
        den[0] += __shfl_xor(den[0], ofs);
        den[1] += __shfl_xor(den[1], ofs);
        den[2] += __shfl_xor(den[2], ofs);
        den[3] += __shfl_xor(den[3], ofs);
    }
    #pragma unroll
    for (int c = 0; c < 4; ++c) {
        int d = c * 16 + l15;
        #pragma unroll
        for (int i2 = 0; i2 < 4; ++i2) {
            size_t idx = (size_t)(b * 256 + rt * 64 + rowT + i2) * 256 + h * 64 + d;
            float ov = bf2f(ob[idx]);
            float sg = 1.f / (1.f + __expf(-ov));
            float dn = fmaxf(fabsf(den[i2]), 1.f);
            hout[idx] = f2bf(sg * accN[c][i2] / dn);
        }
    }
}

// ---------------------------------------------------------------------------
// sLSTM scan. Block=(b,h), 4 waves; wave w owns gate w. R column in 16 f32x4
// regs (d-contiguous via Rt). Raw s_barrier per step: global prefetch and h
// stores stay in flight (no vmcnt drain). Parity-double-buffered gate LDS.
__global__ __launch_bounds__(256) void slstm_scan(
    const unsigned short* __restrict__ zx, const unsigned short* __restrict__ ix,
    const unsigned short* __restrict__ fx, const unsigned short* __restrict__ ox,
    const float* __restrict__ Rt, unsigned short* __restrict__ hout)
{
    int bh = blockIdx.x, b = bh >> 2, h = bh & 3;
    int tid = threadIdx.x, w = tid >> 6, e = tid & 63;
    const float* Rp = Rt + (((size_t)w * 4 + h) * 64 + e) * 64;
    f32x4 r[16];
    #pragma unroll
    for (int j = 0; j < 16; ++j) r[j] = *(const f32x4*)(Rp + j * 4);
    const unsigned short* xin = (w == 0 ? zx : w == 1 ? ix : w == 2 ? fx : ox);
    __shared__ float gl[2][4][64];
    float c = 0.f, n = 0.f, m = 0.f, hv = 0.f;
    size_t base = (size_t)b * 65536 + h * 64 + e;
    unsigned short raw = xin[base];
    for (int t = 0; t < 256; ++t) {
        float gx = bf2f(raw);
        int tn = (t + 1 < 256) ? t + 1 : 255;
        unsigned short rawn = xin[base + (size_t)tn * 256];  // stays in flight
        float a0 = 0.f, a1 = 0.f, a2 = 0.f, a3 = 0.f;
        #pragma unroll
        for (int j = 0; j < 16; ++j) {
            f32x4 rv = r[j];
            a0 += rdlane(hv, 4 * j)     * rv.x;
            a1 += rdlane(hv, 4 * j + 1) * rv.y;
            a2 += rdlane(hv, 4 * j + 2) * rv.z;
            a3 += rdlane(hv, 4 * j + 3) * rv.w;
        }
        gl[t & 1][w][e] = gx + ((a0 + a1) + (a2 + a3));
        __asm__ volatile("s_waitcnt lgkmcnt(0)" ::: "memory");
        __asm__ volatile("s_barrier" ::: "memory");
        float zp = gl[t & 1][0][e], ip = gl[t & 1][1][e];
        float fp = gl[t & 1][2][e], op = gl[t & 1][3][e];
        float ez = __expf(2.f * zp);
        float z  = 1.f - 2.f / (ez + 1.f);          // tanh
        float mn = fmaxf(fp + m, ip);
        float i_s = __expf(ip - mn), f_s = __expf(fp + m - mn);
        m = mn;
        c = f_s * c + i_s * z;
        n = f_s * n + i_s;
        hv = (1.f / (1.f + __expf(-op))) * c / n;
        if (w == 0) hout[base + (size_t)t * 256] = f2bf(hv);
        raw = rawn;
    }
}

// ---------------------------------------------------------------------------
__global__ __launch_bounds__(64) void fc_kernel(
    const float* __restrict__ x, const float* __restrict__ fcW,
    const float* __restrict__ fcb, float* __restrict__ out)
{
    int b = blockIdx.x, lane = threadIdx.x;
    const float* xr = x + ((size_t)b * 256 + 255) * 256;
    float s = 0.f;
    #pragma unroll
    for (int j = 0; j < 4; ++j) { int d = j * 64 + lane; s += xr[d] * fcW[d]; }
    #pragma unroll
    for (int ofs = 32; ofs; ofs >>= 1) s += __shfl_xor(s, ofs);
    if (lane == 0) out[b] = s + fcb[0];
}

// ---------------------------------------------------------------------------
extern "C" void kernel_launch(void* const* d_in, const int* in_sizes, int n_in,
                              void* d_out, int out_size, void* d_ws, size_t ws_size,
                              hipStream_t stream)
{
    const float* X      = (const float*)d_in[0];
    const int*   dyad   = (const int*)d_in[1];
    const float* embed  = (const float*)d_in[2];
    const float* m_ln_g = (const float*)d_in[3];
    const float* m_ln_b = (const float*)d_in[4];
    const float* m_Wq   = (const float*)d_in[5];
    const float* m_Wk   = (const float*)d_in[6];
    const float* m_Wv   = (const float*)d_in[7];
    const float* m_Wi   = (const float*)d_in[8];
    const float* m_Wf   = (const float*)d_in[9];
    const float* m_bi   = (const float*)d_in[10];
    const float* m_bf   = (const float*)d_in[11];
    const float* m_Wo   = (const float*)d_in[12];
    const float* m_Wp   = (const float*)d_in[13];
    const float* s_ln_g = (const float*)d_in[14];
    const float* s_ln_b = (const float*)d_in[15];
    const float* s_Wz   = (const float*)d_in[16];
    const float* s_Wi   = (const float*)d_in[17];
    const float* s_Wf   = (const float*)d_in[18];
    const float* s_Wo   = (const float*)d_in[19];
    const float* s_Rz   = (const float*)d_in[20];
    const float* s_Ri   = (const float*)d_in[21];
    const float* s_Rf   = (const float*)d_in[22];
    const float* s_Ro   = (const float*)d_in[23];
    const float* s_Wp   = (const float*)d_in[24];
    const float* fcW    = (const float*)d_in[25];
    const float* fcb    = (const float*)d_in[26];

    float* ws = (float*)d_ws;
    float* x     = ws;                         // fp32 [8192][256]
    float* gi    = x + SZ;                     // fp32 [8192][4]
    float* gf    = gi + (size_t)BT * 4;
    float* a_arr = gf + (size_t)BT * 4;        // fp32 [128][256]
    float* M_arr = a_arr + 32768;
    float* Rt    = M_arr + 32768;              // fp32 [4][4][64][64]
    unsigned short* xn  = (unsigned short*)(Rt + 65536);     // bf16 [8192][256]
    unsigned short* hb  = xn + SZ;
    unsigned short* g0u = hb + SZ;             // q/z
    unsigned short* g1u = g0u + SZ;            // k/i
    unsigned short* g2u = g1u + SZ;            // v/f
    unsigned short* g3u = g2u + SZ;            // o/o
    unsigned short* Wt  = g3u + SZ;            // bf16 15x[256][256]

    conv_w<<<dim3(4, 4, 15), 256, 0, stream>>>(m_Wq, m_Wk, m_Wv, m_Wo, m_Wp,
                                               s_Wz, s_Wi, s_Wf, s_Wo, s_Wp, Wt);
    transp_r<<<16, 256, 0, stream>>>(s_Rz, s_Ri, s_Rf, s_Ro, Rt);
    build_x<<<8192, 256, 0, stream>>>(X, dyad, embed, x);

    dim3 gg(128, 4);

    auto mlstm = [&](int L) {
        layernorm<<<BT / 4, 256, 0, stream>>>(x, m_ln_g + L * 256, m_ln_b + L * 256, xn);
        gemm_mfma_bf16<<<dim3(128, 4, 4), 256, 0, stream>>>(
            xn, Wt, L * 10, g0u, 1.f, 0.125f, 1.f, 1.f);
        gate_gemm<<<BT / 64, 256, 0, stream>>>(xn, m_Wi + L * 1024, m_Wf + L * 1024,
                                               m_bi + L * 4, m_bf + L * 4, gi, gf);
        scan_am<<<128, 256, 0, stream>>>(gi, gf, a_arr, M_arr);
        mlstm_attn<<<gg, 256, 0, stream>>>(g0u, g1u, g2u, g3u, a_arr, M_arr, hb);
        gemm_mfma_f32<<<dim3(128, 4, 1), 256, 0, stream>>>(hb, Wt, L * 10 + 4, x, x);
    };

    mlstm(0);

    layernorm<<<BT / 4, 256, 0, stream>>>(x, s_ln_g, s_ln_b, xn);
    gemm_mfma_bf16<<<dim3(128, 4, 4), 256, 0, stream>>>(
        xn, Wt, 5, g0u, 1.f, 1.f, 1.f, 1.f);
    slstm_scan<<<128, 256, 0, stream>>>(g0u, g1u, g2u, g3u, Rt, hb);
    gemm_mfma_f32<<<dim3(128, 4, 1), 256, 0, stream>>>(hb, Wt, 9, x, x);

    mlstm(1);

    fc_kernel<<<32, 64, 0, stream>>>(x, fcW, fcb, (float*)d_out);
}

// Round 7
// 376.577 us; speedup vs baseline: 1.0213x; 1.0213x over previous
//
#include <hip/hip_runtime.h>
#include <hip/hip_bf16.h>

// ---------------------------------------------------------------------------
// DyadXLSTM forward. fp32 in/out; bf16 activations into MFMA GEMMs.
// mLSTM recurrence = chunked causal decay-attention (exact rewrite).
// sLSTM sequential scan: register-resident R (pre-transposed, launch_bounds
// (256,1) so the allocator can hold 64 VGPRs of R), readlane broadcast,
// raw s_barrier (no vmcnt drain), distance-2 input prefetch.
// B=32 T=256 NH=4 DH=64 D=H=256, BT=8192.
// ---------------------------------------------------------------------------

#define BT 8192
#define SZ ((size_t)BT * 256)

typedef __attribute__((ext_vector_type(4))) float  f32x4;
typedef __attribute__((ext_vector_type(8))) short  s16x8;

__device__ __forceinline__ float bf2f(unsigned short u) {
    return __uint_as_float(((unsigned int)u) << 16);
}
__device__ __forceinline__ unsigned short f2bf(float f) {
    __hip_bfloat16 h = __float2bfloat16(f);
    return *(unsigned short*)&h;
}
__device__ __forceinline__ float rdlane(float v, int l) {
    return __int_as_float(__builtin_amdgcn_readlane(__float_as_int(v), l));
}

// ---------------------------------------------------------------------------
// Convert+transpose 15 weight matrices (256x256 fp32 K-major) -> bf16 Wt[slot][N][K]
__global__ __launch_bounds__(256) void conv_w(
    const float* mWq, const float* mWk, const float* mWv, const float* mWo,
    const float* mWp, const float* sWz, const float* sWi, const float* sWf,
    const float* sWo, const float* sWp, unsigned short* __restrict__ Wt)
{
    int z = blockIdx.z;
    const float* mp[5] = {mWq, mWk, mWv, mWo, mWp};
    const float* sp[5] = {sWz, sWi, sWf, sWo, sWp};
    const float* src;
    if (z < 5)       src = mp[z];
    else if (z < 10) src = sp[z - 5];
    else             src = mp[z - 10] + 65536;
    int kB = blockIdx.x * 64, nB = blockIdx.y * 64;
    __shared__ unsigned short Ts[64][68];
    int tid = threadIdx.x;
    int r = tid >> 2, c = (tid & 3) * 16;
    #pragma unroll
    for (int j = 0; j < 16; j += 4) {
        float4 wv = *(const float4*)(src + (size_t)(kB + r) * 256 + nB + c + j);
        Ts[r][c + j]     = f2bf(wv.x); Ts[r][c + j + 1] = f2bf(wv.y);
        Ts[r][c + j + 2] = f2bf(wv.z); Ts[r][c + j + 3] = f2bf(wv.w);
    }
    __syncthreads();
    int n = tid >> 2, k0 = (tid & 3) * 16;
    __attribute__((aligned(16))) unsigned short tmp[16];
    #pragma unroll
    for (int j = 0; j < 16; ++j) tmp[j] = Ts[k0 + j][n];
    unsigned short* dst = Wt + (size_t)z * 65536 + (size_t)(nB + n) * 256 + kB + k0;
    *(uint4*)dst       = *(const uint4*)tmp;
    *(uint4*)(dst + 8) = *(const uint4*)(tmp + 8);
}

// ---------------------------------------------------------------------------
// Transpose sLSTM recurrent mats: Rt[gate][h][e][d] = R_gate[h][d][e]
__global__ __launch_bounds__(256) void transp_r(
    const float* __restrict__ Rz, const float* __restrict__ Ri,
    const float* __restrict__ Rf, const float* __restrict__ Ro,
    float* __restrict__ Rt)
{
    int g = blockIdx.x >> 2, h = blockIdx.x & 3;
    const float* R = (g == 0 ? Rz : g == 1 ? Ri : g == 2 ? Rf : Ro) + h * 4096;
    __shared__ float Ts[64][65];
    int tid = threadIdx.x;
    int d = tid >> 2, c4 = (tid & 3) * 16;
    #pragma unroll
    for (int j = 0; j < 16; j += 4)
        *(float4*)&Ts[d][c4 + j] = *(const float4*)(R + d * 64 + c4 + j);
    __syncthreads();
    int e = tid >> 2;
    #pragma unroll
    for (int j = 0; j < 16; j += 4) {
        float4 v = make_float4(Ts[c4 + j][e], Ts[c4 + j + 1][e],
                               Ts[c4 + j + 2][e], Ts[c4 + j + 3][e]);
        *(float4*)(Rt + (((size_t)g * 4 + h) * 64 + e) * 64 + c4 + j) = v;
    }
}

// ---------------------------------------------------------------------------
__global__ __launch_bounds__(256) void build_x(
    const float* __restrict__ X, const int* __restrict__ dyad,
    const float* __restrict__ embed, float* __restrict__ x)
{
    int i = blockIdx.x * 256 + threadIdx.x;
    int d = i & 255, bt = i >> 8, b = bt >> 8;
    x[i] = (d < 224) ? X[bt * 224 + d] : embed[dyad[b] * 32 + (d - 224)];
}

// ---------------------------------------------------------------------------
// LayerNorm: one WAVE per row, 4 elems/lane, no LDS, no barriers.
__global__ __launch_bounds__(256) void layernorm(
    const float* __restrict__ x, const float* __restrict__ g,
    const float* __restrict__ b, unsigned short* __restrict__ xn)
{
    int row = blockIdx.x * 4 + (threadIdx.x >> 6);
    int lane = threadIdx.x & 63;
    float4 v = *(const float4*)(x + (size_t)row * 256 + lane * 4);
    float s  = v.x + v.y + v.z + v.w;
    float s2 = v.x * v.x + v.y * v.y + v.z * v.z + v.w * v.w;
    #pragma unroll
    for (int o = 32; o; o >>= 1) { s += __shfl_xor(s, o); s2 += __shfl_xor(s2, o); }
    float mu  = s * (1.f / 256.f);
    float var = s2 * (1.f / 256.f) - mu * mu;
    float inv = rsqrtf(var + 1e-5f);
    float4 gv = *(const float4*)(g + lane * 4);
    float4 bv = *(const float4*)(b + lane * 4);
    ushort4 o4;
    o4.x = f2bf((v.x - mu) * inv * gv.x + bv.x);
    o4.y = f2bf((v.y - mu) * inv * gv.y + bv.y);
    o4.z = f2bf((v.z - mu) * inv * gv.z + bv.z);
    o4.w = f2bf((v.w - mu) * inv * gv.w + bv.w);
    *(ushort4*)(xn + (size_t)row * 256 + lane * 4) = o4;
}

// ---------------------------------------------------------------------------
// bf16-out GEMM: out[z][8192][256](bf16) = alpha_z * A(bf16) @ Wt[slot0+z]^T
__global__ __launch_bounds__(256) void gemm_mfma_bf16(
    const unsigned short* __restrict__ A, const unsigned short* __restrict__ Wt,
    int slot0, unsigned short* out0, float a0, float a1, float a2, float a3)
{
    __shared__ unsigned short As[64 * 40];
    __shared__ unsigned short Bs[64 * 40];
    int tid = threadIdx.x, bz = blockIdx.z;
    const unsigned short* W = Wt + (size_t)(slot0 + bz) * 65536;
    unsigned short* out = out0 + (size_t)bz * SZ;
    float alpha = bz == 0 ? a0 : bz == 1 ? a1 : bz == 2 ? a2 : a3;
    int rowBase = blockIdx.x * 64, colBase = blockIdx.y * 64;
    int srow = tid >> 2, scol = (tid & 3) * 8;
    const unsigned short* Ap = A + (size_t)(rowBase + srow) * 256 + scol;
    const unsigned short* Wp = W + (size_t)(colBase + srow) * 256 + scol;
    unsigned short* Asw = As + srow * 40 + scol;
    unsigned short* Bsw = Bs + srow * 40 + scol;
    int w = tid >> 6, lane = tid & 63, quad = lane >> 4, l15 = lane & 15;
    const unsigned short* Ar  = As + (w * 16 + l15) * 40 + quad * 8;
    const unsigned short* Br0 = Bs + l15 * 40 + quad * 8;
    f32x4 acc[4];
    #pragma unroll
    for (int c = 0; c < 4; ++c) acc[c] = (f32x4){0.f, 0.f, 0.f, 0.f};
    for (int k0 = 0; k0 < 256; k0 += 32) {
        uint4 av = *(const uint4*)(Ap + k0);
        uint4 bv = *(const uint4*)(Wp + k0);
        __syncthreads();
        *(uint4*)Asw = av;
        *(uint4*)Bsw = bv;
        __syncthreads();
        s16x8 af = *(const s16x8*)Ar;
        #pragma unroll
        for (int c = 0; c < 4; ++c) {
            s16x8 bf = *(const s16x8*)(Br0 + c * 16 * 40);
            acc[c] = __builtin_amdgcn_mfma_f32_16x16x32_bf16(af, bf, acc[c], 0, 0, 0);
        }
    }
    #pragma unroll
    for (int c = 0; c < 4; ++c) {
        int col  = colBase + c * 16 + l15;
        int row0 = rowBase + w * 16 + quad * 4;
        #pragma unroll
        for (int i2 = 0; i2 < 4; ++i2)
            out[(size_t)(row0 + i2) * 256 + col] = f2bf(alpha * acc[c][i2]);
    }
}

// ---------------------------------------------------------------------------
// fp32-out GEMM with residual: out = A(bf16) @ Wt[slot]^T + Res
__global__ __launch_bounds__(256) void gemm_mfma_f32(
    const unsigned short* __restrict__ A, const unsigned short* __restrict__ Wt,
    int slot, float* __restrict__ out, const float* __restrict__ Res)
{
    __shared__ unsigned short As[64 * 40];
    __shared__ unsigned short Bs[64 * 40];
    int tid = threadIdx.x;
    const unsigned short* W = Wt + (size_t)slot * 65536;
    int rowBase = blockIdx.x * 64, colBase = blockIdx.y * 64;
    int srow = tid >> 2, scol = (tid & 3) * 8;
    const unsigned short* Ap = A + (size_t)(rowBase + srow) * 256 + scol;
    const unsigned short* Wp = W + (size_t)(colBase + srow) * 256 + scol;
    unsigned short* Asw = As + srow * 40 + scol;
    unsigned short* Bsw = Bs + srow * 40 + scol;
    int w = tid >> 6, lane = tid & 63, quad = lane >> 4, l15 = lane & 15;
    const unsigned short* Ar  = As + (w * 16 + l15) * 40 + quad * 8;
    const unsigned short* Br0 = Bs + l15 * 40 + quad * 8;
    f32x4 acc[4];
    #pragma unroll
    for (int c = 0; c < 4; ++c) acc[c] = (f32x4){0.f, 0.f, 0.f, 0.f};
    for (int k0 = 0; k0 < 256; k0 += 32) {
        uint4 av = *(const uint4*)(Ap + k0);
        uint4 bv = *(const uint4*)(Wp + k0);
        __syncthreads();
        *(uint4*)Asw = av;
        *(uint4*)Bsw = bv;
        __syncthreads();
        s16x8 af = *(const s16x8*)Ar;
        #pragma unroll
        for (int c = 0; c < 4; ++c) {
            s16x8 bf = *(const s16x8*)(Br0 + c * 16 * 40);
            acc[c] = __builtin_amdgcn_mfma_f32_16x16x32_bf16(af, bf, acc[c], 0, 0, 0);
        }
    }
    #pragma unroll
    for (int c = 0; c < 4; ++c) {
        int col  = colBase + c * 16 + l15;
        int row0 = rowBase + w * 16 + quad * 4;
        #pragma unroll
        for (int i2 = 0; i2 < 4; ++i2) {
            size_t idx = (size_t)(row0 + i2) * 256 + col;
            out[idx] = acc[c][i2] + Res[idx];
        }
    }
}

// ---------------------------------------------------------------------------
// gi/gf[row,h] = xn[row,:].W{i,f}[:,h] + b{i,f}[h]
__global__ __launch_bounds__(256) void gate_gemm(
    const unsigned short* __restrict__ xn,
    const float* __restrict__ Wi, const float* __restrict__ Wf,
    const float* __restrict__ bi, const float* __restrict__ bf_,
    float* __restrict__ gi, float* __restrict__ gf)
{
    int tid = threadIdx.x;
    int hh = tid & 3;
    int row = blockIdx.x * 64 + (tid >> 2);
    float ai = bi[hh], af = bf_[hh];
    const unsigned short* xr = xn + (size_t)row * 256;
    for (int k2 = 0; k2 < 256; ++k2) {
        float xv = bf2f(xr[k2]);
        ai += xv * Wi[k2 * 4 + hh];
        af += xv * Wf[k2 * 4 + hh];
    }
    gi[row * 4 + hh] = ai;
    gf[row * 4 + hh] = af;
}

// ---------------------------------------------------------------------------
// Per-(b,h): F = cumsum(fp); a = ip - F; M = max(0, prefix-max(a)).
__global__ __launch_bounds__(256) void scan_am(
    const float* __restrict__ gi, const float* __restrict__ gf,
    float* __restrict__ a_arr, float* __restrict__ M_arr)
{
    int bh = blockIdx.x, b = bh >> 2, h = bh & 3;
    int t = threadIdx.x;
    float fp = gf[(b * 256 + t) * 4 + h];
    float ip = gi[(b * 256 + t) * 4 + h];
    __shared__ float buf[256];
    buf[t] = fp;
    __syncthreads();
    #pragma unroll
    for (int o = 1; o < 256; o <<= 1) {
        float add = (t >= o) ? buf[t - o] : 0.f;
        __syncthreads();
        buf[t] += add;
        __syncthreads();
    }
    float F = buf[t];
    float a = ip - F;
    __syncthreads();
    buf[t] = a;
    __syncthreads();
    #pragma unroll
    for (int o = 1; o < 256; o <<= 1) {
        float mx = (t >= o) ? buf[t - o] : -3.4e38f;
        __syncthreads();
        buf[t] = fmaxf(buf[t], mx);
        __syncthreads();
    }
    a_arr[bh * 256 + t] = a;
    M_arr[bh * 256 + t] = fmaxf(buf[t], 0.f);
}

// ---------------------------------------------------------------------------
// mLSTM as causal decay-attention. Block = (bh, row-tile rt of 64).
__global__ __launch_bounds__(256) void mlstm_attn(
    const unsigned short* __restrict__ qb, const unsigned short* __restrict__ kb,
    const unsigned short* __restrict__ vb, const unsigned short* __restrict__ ob,
    const float* __restrict__ a_arr, const float* __restrict__ M_arr,
    unsigned short* __restrict__ hout)
{
    int bh = blockIdx.x, rt = blockIdx.y;
    int b = bh >> 2, h = bh & 3;
    int tid = threadIdx.x, w = tid >> 6, lane = tid & 63;
    int quad = lane >> 4, l15 = lane & 15;
    __shared__ unsigned short Qs[64][72];
    __shared__ unsigned short Ks[64][72];
    __shared__ unsigned short Vt[64][72];
    __shared__ unsigned short Ps[4][16][72];
    __shared__ float a_s[64], M_s[64];
    int sr = tid >> 2, sc = (tid & 3) * 16;
    size_t qoff = (size_t)(b * 256 + rt * 64 + sr) * 256 + h * 64 + sc;
    *(uint4*)&Qs[sr][sc]     = *(const uint4*)(qb + qoff);
    *(uint4*)&Qs[sr][sc + 8] = *(const uint4*)(qb + qoff + 8);
    if (tid < 64) M_s[tid] = M_arr[bh * 256 + rt * 64 + tid];
    f32x4 accN[4];
    #pragma unroll
    for (int c = 0; c < 4; ++c) accN[c] = (f32x4){0.f, 0.f, 0.f, 0.f};
    f32x4 den = (f32x4){0.f, 0.f, 0.f, 0.f};
    int rowT = w * 16 + quad * 4;
    for (int ct = 0; ct <= rt; ++ct) {
        size_t koff = (size_t)(b * 256 + ct * 64 + sr) * 256 + h * 64 + sc;
        uint4 kv0 = *(const uint4*)(kb + koff);
        uint4 kv1 = *(const uint4*)(kb + koff + 8);
        uint4 vv0 = *(const uint4*)(vb + koff);
        uint4 vv1 = *(const uint4*)(vb + koff + 8);
        *(uint4*)&Ks[sr][sc]     = kv0;
        *(uint4*)&Ks[sr][sc + 8] = kv1;
        __attribute__((aligned(16))) unsigned short vt[16];
        *(uint4*)vt = vv0; *(uint4*)(vt + 8) = vv1;
        #pragma unroll
        for (int jj = 0; jj < 16; ++jj) Vt[sc + jj][sr] = vt[jj];
        if (tid < 64) a_s[tid] = a_arr[bh * 256 + ct * 64 + tid];
        __syncthreads();
        f32x4 S[4];
        #pragma unroll
        for (int c = 0; c < 4; ++c) S[c] = (f32x4){0.f, 0.f, 0.f, 0.f};
        #pragma unroll
        for (int ks = 0; ks < 2; ++ks) {
            s16x8 af = *(const s16x8*)&Qs[w * 16 + l15][quad * 8 + ks * 32];
            #pragma unroll
            for (int c = 0; c < 4; ++c) {
                s16x8 bfr = *(const s16x8*)&Ks[c * 16 + l15][quad * 8 + ks * 32];
                S[c] = __builtin_amdgcn_mfma_f32_16x16x32_bf16(af, bfr, S[c], 0, 0, 0);
            }
        }
        bool dg = (ct == rt);
        #pragma unroll
        for (int c = 0; c < 4; ++c) {
            int col = c * 16 + l15;
            #pragma unroll
            for (int i2 = 0; i2 < 4; ++i2) {
                int row = rowT + i2;
                float p = S[c][i2] * __expf(a_s[col] - M_s[row]);
                if (dg && col > row) p = 0.f;
                S[c][i2] = p;
                den[i2] += p;
            }
        }
        #pragma unroll
        for (int c = 0; c < 4; ++c)
            #pragma unroll
            for (int i2 = 0; i2 < 4; ++i2)
                Ps[w][quad * 4 + i2][c * 16 + l15] = f2bf(S[c][i2]);
        __syncthreads();
        #pragma unroll
        for (int ks = 0; ks < 2; ++ks) {
            s16x8 af = *(const s16x8*)&Ps[w][l15][quad * 8 + ks * 32];
            #pragma unroll
            for (int c = 0; c < 4; ++c) {
                s16x8 bfr = *(const s16x8*)&Vt[c * 16 + l15][quad * 8 + ks * 32];
                accN[c] = __builtin_amdgcn_mfma_f32_16x16x32_bf16(af, bfr, accN[c], 0, 0, 0);
            }
        }
        __syncthreads();
    }
    #pragma unroll
    for (int ofs = 1; ofs < 16; ofs <<= 1) {
        den[0] += __shfl_xor(den[0], ofs);
        den[1] += __shfl_xor(den[1], ofs);
        den[2] += __shfl_xor(den[2], ofs);
        den[3] += __shfl_xor(den[3], ofs);
    }
    #pragma unroll
    for (int c = 0; c < 4; ++c) {
        int d = c * 16 + l15;
        #pragma unroll
        for (int i2 = 0; i2 < 4; ++i2) {
            size_t idx = (size_t)(b * 256 + rt * 64 + rowT + i2) * 256 + h * 64 + d;
            float ov = bf2f(ob[idx]);
            float sg = 1.f / (1.f + __expf(-ov));
            float dn = fmaxf(fabsf(den[i2]), 1.f);
            hout[idx] = f2bf(sg * accN[c][i2] / dn);
        }
    }
}

// ---------------------------------------------------------------------------
// sLSTM scan. Block=(b,h), 4 waves; wave w owns gate w. R column in 16 f32x4
// regs (d-contiguous via Rt) — launch_bounds(256,1) gives the allocator the
// VGPR budget to keep them resident (1 block/CU is our occupancy anyway:
// 128 blocks on 256 CUs). Raw s_barrier per step (no vmcnt drain) so the
// distance-2 gate prefetch and the h store stay in flight across steps.
__global__ __launch_bounds__(256, 1) void slstm_scan(
    const unsigned short* __restrict__ zx, const unsigned short* __restrict__ ix,
    const unsigned short* __restrict__ fx, const unsigned short* __restrict__ ox,
    const float* __restrict__ Rt, unsigned short* __restrict__ hout)
{
    int bh = blockIdx.x, b = bh >> 2, h = bh & 3;
    int tid = threadIdx.x, w = tid >> 6, e = tid & 63;
    const float* Rp = Rt + (((size_t)w * 4 + h) * 64 + e) * 64;
    f32x4 r[16];
    #pragma unroll
    for (int j = 0; j < 16; ++j) r[j] = *(const f32x4*)(Rp + j * 4);
    const unsigned short* xin = (w == 0 ? zx : w == 1 ? ix : w == 2 ? fx : ox);
    __shared__ float gl[2][4][64];
    float c = 0.f, n = 0.f, m = 0.f, hv = 0.f;
    size_t base = (size_t)b * 65536 + h * 64 + e;
    unsigned short raw0 = xin[base];
    unsigned short raw1 = xin[base + 256];
    for (int t = 0; t < 256; ++t) {
        float gx = bf2f(raw0);
        int tn = (t + 2 < 256) ? t + 2 : 255;
        unsigned short raw2 = xin[base + (size_t)tn * 256];  // distance-2 prefetch
        float a0 = 0.f, a1 = 0.f, a2 = 0.f, a3 = 0.f;
        #pragma unroll
        for (int j = 0; j < 16; ++j) {
            f32x4 rv = r[j];
            a0 += rdlane(hv, 4 * j)     * rv.x;
            a1 += rdlane(hv, 4 * j + 1) * rv.y;
            a2 += rdlane(hv, 4 * j + 2) * rv.z;
            a3 += rdlane(hv, 4 * j + 3) * rv.w;
        }
        gl[t & 1][w][e] = gx + ((a0 + a1) + (a2 + a3));
        __asm__ volatile("s_waitcnt lgkmcnt(0)" ::: "memory");
        __asm__ volatile("s_barrier" ::: "memory");
        float zp = gl[t & 1][0][e], ip = gl[t & 1][1][e];
        float fp = gl[t & 1][2][e], op = gl[t & 1][3][e];
        float ez = __expf(2.f * zp);
        float z  = 1.f - 2.f / (ez + 1.f);          // tanh
        float mn = fmaxf(fp + m, ip);
        float i_s = __expf(ip - mn), f_s = __expf(fp + m - mn);
        m = mn;
        c = f_s * c + i_s * z;
        n = f_s * n + i_s;
        hv = (1.f / (1.f + __expf(-op))) * c / n;
        if (w == 0) hout[base + (size_t)t * 256] = f2bf(hv);
        raw0 = raw1; raw1 = raw2;
    }
}

// ---------------------------------------------------------------------------
__global__ __launch_bounds__(64) void fc_kernel(
    const float* __restrict__ x, const float* __restrict__ fcW,
    const float* __restrict__ fcb, float* __restrict__ out)
{
    int b = blockIdx.x, lane = threadIdx.x;
    const float* xr = x + ((size_t)b * 256 + 255) * 256;
    float s = 0.f;
    #pragma unroll
    for (int j = 0; j < 4; ++j) { int d = j * 64 + lane; s += xr[d] * fcW[d]; }
    #pragma unroll
    for (int ofs = 32; ofs; ofs >>= 1) s += __shfl_xor(s, ofs);
    if (lane == 0) out[b] = s + fcb[0];
}

// ---------------------------------------------------------------------------
extern "C" void kernel_launch(void* const* d_in, const int* in_sizes, int n_in,
                              void* d_out, int out_size, void* d_ws, size_t ws_size,
                              hipStream_t stream)
{
    const float* X      = (const float*)d_in[0];
    const int*   dyad   = (const int*)d_in[1];
    const float* embed  = (const float*)d_in[2];
    const float* m_ln_g = (const float*)d_in[3];
    const float* m_ln_b = (const float*)d_in[4];
    const float* m_Wq   = (const float*)d_in[5];
    const float* m_Wk   = (const float*)d_in[6];
    const float* m_Wv   = (const float*)d_in[7];
    const float* m_Wi   = (const float*)d_in[8];
    const float* m_Wf   = (const float*)d_in[9];
    const float* m_bi   = (const float*)d_in[10];
    const float* m_bf   = (const float*)d_in[11];
    const float* m_Wo   = (const float*)d_in[12];
    const float* m_Wp   = (const float*)d_in[13];
    const float* s_ln_g = (const float*)d_in[14];
    const float* s_ln_b = (const float*)d_in[15];
    const float* s_Wz   = (const float*)d_in[16];
    const float* s_Wi   = (const float*)d_in[17];
    const float* s_Wf   = (const float*)d_in[18];
    const float* s_Wo   = (const float*)d_in[19];
    const float* s_Rz   = (const float*)d_in[20];
    const float* s_Ri   = (const float*)d_in[21];
    const float* s_Rf   = (const float*)d_in[22];
    const float* s_Ro   = (const float*)d_in[23];
    const float* s_Wp   = (const float*)d_in[24];
    const float* fcW    = (const float*)d_in[25];
    const float* fcb    = (const float*)d_in[26];

    float* ws = (float*)d_ws;
    float* x     = ws;                         // fp32 [8192][256]
    float* gi    = x + SZ;                     // fp32 [8192][4]
    float* gf    = gi + (size_t)BT * 4;
    float* a_arr = gf + (size_t)BT * 4;        // fp32 [128][256]
    float* M_arr = a_arr + 32768;
    float* Rt    = M_arr + 32768;              // fp32 [4][4][64][64]
    unsigned short* xn  = (unsigned short*)(Rt + 65536);     // bf16 [8192][256]
    unsigned short* hb  = xn + SZ;
    unsigned short* g0u = hb + SZ;             // q/z
    unsigned short* g1u = g0u + SZ;            // k/i
    unsigned short* g2u = g1u + SZ;            // v/f
    unsigned short* g3u = g2u + SZ;            // o/o
    unsigned short* Wt  = g3u + SZ;            // bf16 15x[256][256]

    conv_w<<<dim3(4, 4, 15), 256, 0, stream>>>(m_Wq, m_Wk, m_Wv, m_Wo, m_Wp,
                                               s_Wz, s_Wi, s_Wf, s_Wo, s_Wp, Wt);
    transp_r<<<16, 256, 0, stream>>>(s_Rz, s_Ri, s_Rf, s_Ro, Rt);
    build_x<<<8192, 256, 0, stream>>>(X, dyad, embed, x);

    dim3 gg(128, 4);

    auto mlstm = [&](int L) {
        layernorm<<<BT / 4, 256, 0, stream>>>(x, m_ln_g + L * 256, m_ln_b + L * 256, xn);
        gemm_mfma_bf16<<<dim3(128, 4, 4), 256, 0, stream>>>(
            xn, Wt, L * 10, g0u, 1.f, 0.125f, 1.f, 1.f);
        gate_gemm<<<BT / 64, 256, 0, stream>>>(xn, m_Wi + L * 1024, m_Wf + L * 1024,
                                               m_bi + L * 4, m_bf + L * 4, gi, gf);
        scan_am<<<128, 256, 0, stream>>>(gi, gf, a_arr, M_arr);
        mlstm_attn<<<gg, 256, 0, stream>>>(g0u, g1u, g2u, g3u, a_arr, M_arr, hb);
        gemm_mfma_f32<<<dim3(128, 4, 1), 256, 0, stream>>>(hb, Wt, L * 10 + 4, x, x);
    };

    mlstm(0);

    layernorm<<<BT / 4, 256, 0, stream>>>(x, s_ln_g, s_ln_b, xn);
    gemm_mfma_bf16<<<dim3(128, 4, 4), 256, 0, stream>>>(
        xn, Wt, 5, g0u, 1.f, 1.f, 1.f, 1.f);
    slstm_scan<<<128, 256, 0, stream>>>(g0u, g1u, g2u, g3u, Rt, hb);
    gemm_mfma_f32<<<dim3(128, 4, 1), 256, 0, stream>>>(hb, Wt, 9, x, x);

    mlstm(1);

    fc_kernel<<<32, 64, 0, stream>>>(x, fcW, fcb, (float*)d_out);
}

// Round 8
// 375.761 us; speedup vs baseline: 1.0235x; 1.0022x over previous
//
#include <hip/hip_runtime.h>
#include <hip/hip_bf16.h>

// ---------------------------------------------------------------------------
// DyadXLSTM forward. fp32 in/out; bf16 activations into MFMA GEMMs.
// mLSTM recurrence = chunked causal decay-attention (exact rewrite).
// sLSTM sequential scan: register-resident R (pre-transposed; pinned into
// VGPRs with empty asm so machine-sinking can't push the loads into the
// t-loop), readlane broadcast, raw s_barrier, distance-2 input prefetch.
// B=32 T=256 NH=4 DH=64 D=H=256, BT=8192.
// ---------------------------------------------------------------------------

#define BT 8192
#define SZ ((size_t)BT * 256)

typedef __attribute__((ext_vector_type(4))) float  f32x4;
typedef __attribute__((ext_vector_type(8))) short  s16x8;

__device__ __forceinline__ float bf2f(unsigned short u) {
    return __uint_as_float(((unsigned int)u) << 16);
}
__device__ __forceinline__ unsigned short f2bf(float f) {
    __hip_bfloat16 h = __float2bfloat16(f);
    return *(unsigned short*)&h;
}
__device__ __forceinline__ float rdlane(float v, int l) {
    return __int_as_float(__builtin_amdgcn_readlane(__float_as_int(v), l));
}

// ---------------------------------------------------------------------------
// Convert+transpose 15 weight matrices (256x256 fp32 K-major) -> bf16 Wt[slot][N][K]
__global__ __launch_bounds__(256) void conv_w(
    const float* mWq, const float* mWk, const float* mWv, const float* mWo,
    const float* mWp, const float* sWz, const float* sWi, const float* sWf,
    const float* sWo, const float* sWp, unsigned short* __restrict__ Wt)
{
    int z = blockIdx.z;
    const float* mp[5] = {mWq, mWk, mWv, mWo, mWp};
    const float* sp[5] = {sWz, sWi, sWf, sWo, sWp};
    const float* src;
    if (z < 5)       src = mp[z];
    else if (z < 10) src = sp[z - 5];
    else             src = mp[z - 10] + 65536;
    int kB = blockIdx.x * 64, nB = blockIdx.y * 64;
    __shared__ unsigned short Ts[64][68];
    int tid = threadIdx.x;
    int r = tid >> 2, c = (tid & 3) * 16;
    #pragma unroll
    for (int j = 0; j < 16; j += 4) {
        float4 wv = *(const float4*)(src + (size_t)(kB + r) * 256 + nB + c + j);
        Ts[r][c + j]     = f2bf(wv.x); Ts[r][c + j + 1] = f2bf(wv.y);
        Ts[r][c + j + 2] = f2bf(wv.z); Ts[r][c + j + 3] = f2bf(wv.w);
    }
    __syncthreads();
    int n = tid >> 2, k0 = (tid & 3) * 16;
    __attribute__((aligned(16))) unsigned short tmp[16];
    #pragma unroll
    for (int j = 0; j < 16; ++j) tmp[j] = Ts[k0 + j][n];
    unsigned short* dst = Wt + (size_t)z * 65536 + (size_t)(nB + n) * 256 + kB + k0;
    *(uint4*)dst       = *(const uint4*)tmp;
    *(uint4*)(dst + 8) = *(const uint4*)(tmp + 8);
}

// ---------------------------------------------------------------------------
// Transpose sLSTM recurrent mats: Rt[gate][h][e][d] = R_gate[h][d][e]
__global__ __launch_bounds__(256) void transp_r(
    const float* __restrict__ Rz, const float* __restrict__ Ri,
    const float* __restrict__ Rf, const float* __restrict__ Ro,
    float* __restrict__ Rt)
{
    int g = blockIdx.x >> 2, h = blockIdx.x & 3;
    const float* R = (g == 0 ? Rz : g == 1 ? Ri : g == 2 ? Rf : Ro) + h * 4096;
    __shared__ float Ts[64][65];
    int tid = threadIdx.x;
    int d = tid >> 2, c4 = (tid & 3) * 16;
    #pragma unroll
    for (int j = 0; j < 16; j += 4)
        *(float4*)&Ts[d][c4 + j] = *(const float4*)(R + d * 64 + c4 + j);
    __syncthreads();
    int e = tid >> 2;
    #pragma unroll
    for (int j = 0; j < 16; j += 4) {
        float4 v = make_float4(Ts[c4 + j][e], Ts[c4 + j + 1][e],
                               Ts[c4 + j + 2][e], Ts[c4 + j + 3][e]);
        *(float4*)(Rt + (((size_t)g * 4 + h) * 64 + e) * 64 + c4 + j) = v;
    }
}

// ---------------------------------------------------------------------------
__global__ __launch_bounds__(256) void build_x(
    const float* __restrict__ X, const int* __restrict__ dyad,
    const float* __restrict__ embed, float* __restrict__ x)
{
    int i = blockIdx.x * 256 + threadIdx.x;
    int d = i & 255, bt = i >> 8, b = bt >> 8;
    x[i] = (d < 224) ? X[bt * 224 + d] : embed[dyad[b] * 32 + (d - 224)];
}

// ---------------------------------------------------------------------------
// LayerNorm: one WAVE per row, 4 elems/lane, no LDS, no barriers.
__global__ __launch_bounds__(256) void layernorm(
    const float* __restrict__ x, const float* __restrict__ g,
    const float* __restrict__ b, unsigned short* __restrict__ xn)
{
    int row = blockIdx.x * 4 + (threadIdx.x >> 6);
    int lane = threadIdx.x & 63;
    float4 v = *(const float4*)(x + (size_t)row * 256 + lane * 4);
    float s  = v.x + v.y + v.z + v.w;
    float s2 = v.x * v.x + v.y * v.y + v.z * v.z + v.w * v.w;
    #pragma unroll
    for (int o = 32; o; o >>= 1) { s += __shfl_xor(s, o); s2 += __shfl_xor(s2, o); }
    float mu  = s * (1.f / 256.f);
    float var = s2 * (1.f / 256.f) - mu * mu;
    float inv = rsqrtf(var + 1e-5f);
    float4 gv = *(const float4*)(g + lane * 4);
    float4 bv = *(const float4*)(b + lane * 4);
    ushort4 o4;
    o4.x = f2bf((v.x - mu) * inv * gv.x + bv.x);
    o4.y = f2bf((v.y - mu) * inv * gv.y + bv.y);
    o4.z = f2bf((v.z - mu) * inv * gv.z + bv.z);
    o4.w = f2bf((v.w - mu) * inv * gv.w + bv.w);
    *(ushort4*)(xn + (size_t)row * 256 + lane * 4) = o4;
}

// ---------------------------------------------------------------------------
// bf16-out GEMM: out[z][8192][256](bf16) = alpha_z * A(bf16) @ Wt[slot0+z]^T
__global__ __launch_bounds__(256) void gemm_mfma_bf16(
    const unsigned short* __restrict__ A, const unsigned short* __restrict__ Wt,
    int slot0, unsigned short* out0, float a0, float a1, float a2, float a3)
{
    __shared__ unsigned short As[64 * 40];
    __shared__ unsigned short Bs[64 * 40];
    int tid = threadIdx.x, bz = blockIdx.z;
    const unsigned short* W = Wt + (size_t)(slot0 + bz) * 65536;
    unsigned short* out = out0 + (size_t)bz * SZ;
    float alpha = bz == 0 ? a0 : bz == 1 ? a1 : bz == 2 ? a2 : a3;
    int rowBase = blockIdx.x * 64, colBase = blockIdx.y * 64;
    int srow = tid >> 2, scol = (tid & 3) * 8;
    const unsigned short* Ap = A + (size_t)(rowBase + srow) * 256 + scol;
    const unsigned short* Wp = W + (size_t)(colBase + srow) * 256 + scol;
    unsigned short* Asw = As + srow * 40 + scol;
    unsigned short* Bsw = Bs + srow * 40 + scol;
    int w = tid >> 6, lane = tid & 63, quad = lane >> 4, l15 = lane & 15;
    const unsigned short* Ar  = As + (w * 16 + l15) * 40 + quad * 8;
    const unsigned short* Br0 = Bs + l15 * 40 + quad * 8;
    f32x4 acc[4];
    #pragma unroll
    for (int c = 0; c < 4; ++c) acc[c] = (f32x4){0.f, 0.f, 0.f, 0.f};
    for (int k0 = 0; k0 < 256; k0 += 32) {
        uint4 av = *(const uint4*)(Ap + k0);
        uint4 bv = *(const uint4*)(Wp + k0);
        __syncthreads();
        *(uint4*)Asw = av;
        *(uint4*)Bsw = bv;
        __syncthreads();
        s16x8 af = *(const s16x8*)Ar;
        #pragma unroll
        for (int c = 0; c < 4; ++c) {
            s16x8 bf = *(const s16x8*)(Br0 + c * 16 * 40);
            acc[c] = __builtin_amdgcn_mfma_f32_16x16x32_bf16(af, bf, acc[c], 0, 0, 0);
        }
    }
    #pragma unroll
    for (int c = 0; c < 4; ++c) {
        int col  = colBase + c * 16 + l15;
        int row0 = rowBase + w * 16 + quad * 4;
        #pragma unroll
        for (int i2 = 0; i2 < 4; ++i2)
            out[(size_t)(row0 + i2) * 256 + col] = f2bf(alpha * acc[c][i2]);
    }
}

// ---------------------------------------------------------------------------
// fp32-out GEMM with residual: out = A(bf16) @ Wt[slot]^T + Res
__global__ __launch_bounds__(256) void gemm_mfma_f32(
    const unsigned short* __restrict__ A, const unsigned short* __restrict__ Wt,
    int slot, float* __restrict__ out, const float* __restrict__ Res)
{
    __shared__ unsigned short As[64 * 40];
    __shared__ unsigned short Bs[64 * 40];
    int tid = threadIdx.x;
    const unsigned short* W = Wt + (size_t)slot * 65536;
    int rowBase = blockIdx.x * 64, colBase = blockIdx.y * 64;
    int srow = tid >> 2, scol = (tid & 3) * 8;
    const unsigned short* Ap = A + (size_t)(rowBase + srow) * 256 + scol;
    const unsigned short* Wp = W + (size_t)(colBase + srow) * 256 + scol;
    unsigned short* Asw = As + srow * 40 + scol;
    unsigned short* Bsw = Bs + srow * 40 + scol;
    int w = tid >> 6, lane = tid & 63, quad = lane >> 4, l15 = lane & 15;
    const unsigned short* Ar  = As + (w * 16 + l15) * 40 + quad * 8;
    const unsigned short* Br0 = Bs + l15 * 40 + quad * 8;
    f32x4 acc[4];
    #pragma unroll
    for (int c = 0; c < 4; ++c) acc[c] = (f32x4){0.f, 0.f, 0.f, 0.f};
    for (int k0 = 0; k0 < 256; k0 += 32) {
        uint4 av = *(const uint4*)(Ap + k0);
        uint4 bv = *(const uint4*)(Wp + k0);
        __syncthreads();
        *(uint4*)Asw = av;
        *(uint4*)Bsw = bv;
        __syncthreads();
        s16x8 af = *(const s16x8*)Ar;
        #pragma unroll
        for (int c = 0; c < 4; ++c) {
            s16x8 bf = *(const s16x8*)(Br0 + c * 16 * 40);
            acc[c] = __builtin_amdgcn_mfma_f32_16x16x32_bf16(af, bf, acc[c], 0, 0, 0);
        }
    }
    #pragma unroll
    for (int c = 0; c < 4; ++c) {
        int col  = colBase + c * 16 + l15;
        int row0 = rowBase + w * 16 + quad * 4;
        #pragma unroll
        for (int i2 = 0; i2 < 4; ++i2) {
            size_t idx = (size_t)(row0 + i2) * 256 + col;
            out[idx] = acc[c][i2] + Res[idx];
        }
    }
}

// ---------------------------------------------------------------------------
// gi/gf[row,h] = xn[row,:].W{i,f}[:,h] + b{i,f}[h]
__global__ __launch_bounds__(256) void gate_gemm(
    const unsigned short* __restrict__ xn,
    const float* __restrict__ Wi, const float* __restrict__ Wf,
    const float* __restrict__ bi, const float* __restrict__ bf_,
    float* __restrict__ gi, float* __restrict__ gf)
{
    int tid = threadIdx.x;
    int hh = tid & 3;
    int row = blockIdx.x * 64 + (tid >> 2);
    float ai = bi[hh], af = bf_[hh];
    const unsigned short* xr = xn + (size_t)row * 256;
    for (int k2 = 0; k2 < 256; ++k2) {
        float xv = bf2f(xr[k2]);
        ai += xv * Wi[k2 * 4 + hh];
        af += xv * Wf[k2 * 4 + hh];
    }
    gi[row * 4 + hh] = ai;
    gf[row * 4 + hh] = af;
}

// ---------------------------------------------------------------------------
// Per-(b,h): F = cumsum(fp); a = ip - F; M = max(0, prefix-max(a)).
__global__ __launch_bounds__(256) void scan_am(
    const float* __restrict__ gi, const float* __restrict__ gf,
    float* __restrict__ a_arr, float* __restrict__ M_arr)
{
    int bh = blockIdx.x, b = bh >> 2, h = bh & 3;
    int t = threadIdx.x;
    float fp = gf[(b * 256 + t) * 4 + h];
    float ip = gi[(b * 256 + t) * 4 + h];
    __shared__ float buf[256];
    buf[t] = fp;
    __syncthreads();
    #pragma unroll
    for (int o = 1; o < 256; o <<= 1) {
        float add = (t >= o) ? buf[t - o] : 0.f;
        __syncthreads();
        buf[t] += add;
        __syncthreads();
    }
    float F = buf[t];
    float a = ip - F;
    __syncthreads();
    buf[t] = a;
    __syncthreads();
    #pragma unroll
    for (int o = 1; o < 256; o <<= 1) {
        float mx = (t >= o) ? buf[t - o] : -3.4e38f;
        __syncthreads();
        buf[t] = fmaxf(buf[t], mx);
        __syncthreads();
    }
    a_arr[bh * 256 + t] = a;
    M_arr[bh * 256 + t] = fmaxf(buf[t], 0.f);
}

// ---------------------------------------------------------------------------
// mLSTM as causal decay-attention. Block = (bh, row-tile rt of 64).
__global__ __launch_bounds__(256) void mlstm_attn(
    const unsigned short* __restrict__ qb, const unsigned short* __restrict__ kb,
    const unsigned short* __restrict__ vb, const unsigned short* __restrict__ ob,
    const float* __restrict__ a_arr, const float* __restrict__ M_arr,
    unsigned short* __restrict__ hout)
{
    int bh = blockIdx.x, rt = blockIdx.y;
    int b = bh >> 2, h = bh & 3;
    int tid = threadIdx.x, w = tid >> 6, lane = tid & 63;
    int quad = lane >> 4, l15 = lane & 15;
    __shared__ unsigned short Qs[64][72];
    __shared__ unsigned short Ks[64][72];
    __shared__ unsigned short Vt[64][72];
    __shared__ unsigned short Ps[4][16][72];
    __shared__ float a_s[64], M_s[64];
    int sr = tid >> 2, sc = (tid & 3) * 16;
    size_t qoff = (size_t)(b * 256 + rt * 64 + sr) * 256 + h * 64 + sc;
    *(uint4*)&Qs[sr][sc]     = *(const uint4*)(qb + qoff);
    *(uint4*)&Qs[sr][sc + 8] = *(const uint4*)(qb + qoff + 8);
    if (tid < 64) M_s[tid] = M_arr[bh * 256 + rt * 64 + tid];
    f32x4 accN[4];
    #pragma unroll
    for (int c = 0; c < 4; ++c) accN[c] = (f32x4){0.f, 0.f, 0.f, 0.f};
    f32x4 den = (f32x4){0.f, 0.f, 0.f, 0.f};
    int rowT = w * 16 + quad * 4;
    for (int ct = 0; ct <= rt; ++ct) {
        size_t koff = (size_t)(b * 256 + ct * 64 + sr) * 256 + h * 64 + sc;
        uint4 kv0 = *(const uint4*)(kb + koff);
        uint4 kv1 = *(const uint4*)(kb + koff + 8);
        uint4 vv0 = *(const uint4*)(vb + koff);
        uint4 vv1 = *(const uint4*)(vb + koff + 8);
        *(uint4*)&Ks[sr][sc]     = kv0;
        *(uint4*)&Ks[sr][sc + 8] = kv1;
        __attribute__((aligned(16))) unsigned short vt[16];
        *(uint4*)vt = vv0; *(uint4*)(vt + 8) = vv1;
        #pragma unroll
        for (int jj = 0; jj < 16; ++jj) Vt[sc + jj][sr] = vt[jj];
        if (tid < 64) a_s[tid] = a_arr[bh * 256 + ct * 64 + tid];
        __syncthreads();
        f32x4 S[4];
        #pragma unroll
        for (int c = 0; c < 4; ++c) S[c] = (f32x4){0.f, 0.f, 0.f, 0.f};
        #pragma unroll
        for (int ks = 0; ks < 2; ++ks) {
            s16x8 af = *(const s16x8*)&Qs[w * 16 + l15][quad * 8 + ks * 32];
            #pragma unroll
            for (int c = 0; c < 4; ++c) {
                s16x8 bfr = *(const s16x8*)&Ks[c * 16 + l15][quad * 8 + ks * 32];
                S[c] = __builtin_amdgcn_mfma_f32_16x16x32_bf16(af, bfr, S[c], 0, 0, 0);
            }
        }
        bool dg = (ct == rt);
        #pragma unroll
        for (int c = 0; c < 4; ++c) {
            int col = c * 16 + l15;
            #pragma unroll
            for (int i2 = 0; i2 < 4; ++i2) {
                int row = rowT + i2;
                float p = S[c][i2] * __expf(a_s[col] - M_s[row]);
                if (dg && col > row) p = 0.f;
                S[c][i2] = p;
                den[i2] += p;
            }
        }
        #pragma unroll
        for (int c = 0; c < 4; ++c)
            #pragma unroll
            for (int i2 = 0; i2 < 4; ++i2)
                Ps[w][quad * 4 + i2][c * 16 + l15] = f2bf(S[c][i2]);
        __syncthreads();
        #pragma unroll
        for (int ks = 0; ks < 2; ++ks) {
            s16x8 af = *(const s16x8*)&Ps[w][l15][quad * 8 + ks * 32];
            #pragma unroll
            for (int c = 0; c < 4; ++c) {
                s16x8 bfr = *(const s16x8*)&Vt[c * 16 + l15][quad * 8 + ks * 32];
                accN[c] = __builtin_amdgcn_mfma_f32_16x16x32_bf16(af, bfr, accN[c], 0, 0, 0);
            }
        }
        __syncthreads();
    }
    #pragma unroll
    for (int ofs = 1; ofs < 16; ofs <<= 1) {
        den[0] += __shfl_xor(den[0], ofs);
        den[1] += __shfl_xor(den[1], ofs);
        den[2] += __shfl_xor(den[2], ofs);
        den[3] += __shfl_xor(den[3], ofs);
    }
    #pragma unroll
    for (int c = 0; c < 4; ++c) {
        int d = c * 16 + l15;
        #pragma unroll
        for (int i2 = 0; i2 < 4; ++i2) {
            size_t idx = (size_t)(b * 256 + rt * 64 + rowT + i2) * 256 + h * 64 + d;
            float ov = bf2f(ob[idx]);
            float sg = 1.f / (1.f + __expf(-ov));
            float dn = fmaxf(fabsf(den[i2]), 1.f);
            hout[idx] = f2bf(sg * accN[c][i2] / dn);
        }
    }
}

// ---------------------------------------------------------------------------
// sLSTM scan. Block=(b,h), 4 waves; wave w owns gate w. R column in 16 f32x4
// regs, PINNED via empty asm so the loads can't be sunk into the t-loop
// (round-6/7 showed VGPR=48..52 => compiler kept reloading R every step).
// Raw s_barrier per step (no vmcnt drain); distance-2 gate prefetch.
__global__ __launch_bounds__(256, 1) void slstm_scan(
    const unsigned short* __restrict__ zx, const unsigned short* __restrict__ ix,
    const unsigned short* __restrict__ fx, const unsigned short* __restrict__ ox,
    const float* __restrict__ Rt, unsigned short* __restrict__ hout)
{
    int bh = blockIdx.x, b = bh >> 2, h = bh & 3;
    int tid = threadIdx.x, w = tid >> 6, e = tid & 63;
    const float* Rp = Rt + (((size_t)w * 4 + h) * 64 + e) * 64;
    f32x4 r[16];
    #pragma unroll
    for (int j = 0; j < 16; ++j) r[j] = *(const f32x4*)(Rp + j * 4);
    // Pin: force all 16 f32x4 into VGPRs here; loads cannot sink past this.
    #pragma unroll
    for (int j = 0; j < 16; ++j)
        __asm__ volatile("" : "+v"(r[j]));
    const unsigned short* xin = (w == 0 ? zx : w == 1 ? ix : w == 2 ? fx : ox);
    __shared__ float gl[2][4][64];
    float c = 0.f, n = 0.f, m = 0.f, hv = 0.f;
    size_t base = (size_t)b * 65536 + h * 64 + e;
    unsigned short raw0 = xin[base];
    unsigned short raw1 = xin[base + 256];
    for (int t = 0; t < 256; ++t) {
        float gx = bf2f(raw0);
        int tn = (t + 2 < 256) ? t + 2 : 255;
        unsigned short raw2 = xin[base + (size_t)tn * 256];  // distance-2 prefetch
        float a0 = 0.f, a1 = 0.f, a2 = 0.f, a3 = 0.f;
        #pragma unroll
        for (int j = 0; j < 16; ++j) {
            f32x4 rv = r[j];
            a0 += rdlane(hv, 4 * j)     * rv.x;
            a1 += rdlane(hv, 4 * j + 1) * rv.y;
            a2 += rdlane(hv, 4 * j + 2) * rv.z;
            a3 += rdlane(hv, 4 * j + 3) * rv.w;
        }
        gl[t & 1][w][e] = gx + ((a0 + a1) + (a2 + a3));
        __asm__ volatile("s_waitcnt lgkmcnt(0)" ::: "memory");
        __asm__ volatile("s_barrier" ::: "memory");
        float zp = gl[t & 1][0][e], ip = gl[t & 1][1][e];
        float fp = gl[t & 1][2][e], op = gl[t & 1][3][e];
        float ez = __expf(2.f * zp);
        float z  = 1.f - 2.f / (ez + 1.f);          // tanh
        float mn = fmaxf(fp + m, ip);
        float i_s = __expf(ip - mn), f_s = __expf(fp + m - mn);
        m = mn;
        c = f_s * c + i_s * z;
        n = f_s * n + i_s;
        hv = (1.f / (1.f + __expf(-op))) * c / n;
        if (w == 0) hout[base + (size_t)t * 256] = f2bf(hv);
        raw0 = raw1; raw1 = raw2;
    }
}

// ---------------------------------------------------------------------------
__global__ __launch_bounds__(64) void fc_kernel(
    const float* __restrict__ x, const float* __restrict__ fcW,
    const float* __restrict__ fcb, float* __restrict__ out)
{
    int b = blockIdx.x, lane = threadIdx.x;
    const float* xr = x + ((size_t)b * 256 + 255) * 256;
    float s = 0.f;
    #pragma unroll
    for (int j = 0; j < 4; ++j) { int d = j * 64 + lane; s += xr[d] * fcW[d]; }
    #pragma unroll
    for (int ofs = 32; ofs; ofs >>= 1) s += __shfl_xor(s, ofs);
    if (lane == 0) out[b] = s + fcb[0];
}

// ---------------------------------------------------------------------------
extern "C" void kernel_launch(void* const* d_in, const int* in_sizes, int n_in,
                              void* d_out, int out_size, void* d_ws, size_t ws_size,
                              hipStream_t stream)
{
    const float* X      = (const float*)d_in[0];
    const int*   dyad   = (const int*)d_in[1];
    const float* embed  = (const float*)d_in[2];
    const float* m_ln_g = (const float*)d_in[3];
    const float* m_ln_b = (const float*)d_in[4];
    const float* m_Wq   = (const float*)d_in[5];
    const float* m_Wk   = (const float*)d_in[6];
    const float* m_Wv   = (const float*)d_in[7];
    const float* m_Wi   = (const float*)d_in[8];
    const float* m_Wf   = (const float*)d_in[9];
    const float* m_bi   = (const float*)d_in[10];
    const float* m_bf   = (const float*)d_in[11];
    const float* m_Wo   = (const float*)d_in[12];
    const float* m_Wp   = (const float*)d_in[13];
    const float* s_ln_g = (const float*)d_in[14];
    const float* s_ln_b = (const float*)d_in[15];
    const float* s_Wz   = (const float*)d_in[16];
    const float* s_Wi   = (const float*)d_in[17];
    const float* s_Wf   = (const float*)d_in[18];
    const float* s_Wo   = (const float*)d_in[19];
    const float* s_Rz   = (const float*)d_in[20];
    const float* s_Ri   = (const float*)d_in[21];
    const float* s_Rf   = (const float*)d_in[22];
    const float* s_Ro   = (const float*)d_in[23];
    const float* s_Wp   = (const float*)d_in[24];
    const float* fcW    = (const float*)d_in[25];
    const float* fcb    = (const float*)d_in[26];

    float* ws = (float*)d_ws;
    float* x     = ws;                         // fp32 [8192][256]
    float* gi    = x + SZ;                     // fp32 [8192][4]
    float* gf    = gi + (size_t)BT * 4;
    float* a_arr = gf + (size_t)BT * 4;        // fp32 [128][256]
    float* M_arr = a_arr + 32768;
    float* Rt    = M_arr + 32768;              // fp32 [4][4][64][64]
    unsigned short* xn  = (unsigned short*)(Rt + 65536);     // bf16 [8192][256]
    unsigned short* hb  = xn + SZ;
    unsigned short* g0u = hb + SZ;             // q/z
    unsigned short* g1u = g0u + SZ;            // k/i
    unsigned short* g2u = g1u + SZ;            // v/f
    unsigned short* g3u = g2u + SZ;            // o/o
    unsigned short* Wt  = g3u + SZ;            // bf16 15x[256][256]

    conv_w<<<dim3(4, 4, 15), 256, 0, stream>>>(m_Wq, m_Wk, m_Wv, m_Wo, m_Wp,
                                               s_Wz, s_Wi, s_Wf, s_Wo, s_Wp, Wt);
    transp_r<<<16, 256, 0, stream>>>(s_Rz, s_Ri, s_Rf, s_Ro, Rt);
    build_x<<<8192, 256, 0, stream>>>(X, dyad, embed, x);

    dim3 gg(128, 4);

    auto mlstm = [&](int L) {
        layernorm<<<BT / 4, 256, 0, stream>>>(x, m_ln_g + L * 256, m_ln_b + L * 256, xn);
        gemm_mfma_bf16<<<dim3(128, 4, 4), 256, 0, stream>>>(
            xn, Wt, L * 10, g0u, 1.f, 0.125f, 1.f, 1.f);
        gate_gemm<<<BT / 64, 256, 0, stream>>>(xn, m_Wi + L * 1024, m_Wf + L * 1024,
                                               m_bi + L * 4, m_bf + L * 4, gi, gf);
        scan_am<<<128, 256, 0, stream>>>(gi, gf, a_arr, M_arr);
        mlstm_attn<<<gg, 256, 0, stream>>>(g0u, g1u, g2u, g3u, a_arr, M_arr, hb);
        gemm_mfma_f32<<<dim3(128, 4, 1), 256, 0, stream>>>(hb, Wt, L * 10 + 4, x, x);
    };

    mlstm(0);

    layernorm<<<BT / 4, 256, 0, stream>>>(x, s_ln_g, s_ln_b, xn);
    gemm_mfma_bf16<<<dim3(128, 4, 4), 256, 0, stream>>>(
        xn, Wt, 5, g0u, 1.f, 1.f, 1.f, 1.f);
    slstm_scan<<<128, 256, 0, stream>>>(g0u, g1u, g2u, g3u, Rt, hb);
    gemm_mfma_f32<<<dim3(128, 4, 1), 256, 0, stream>>>(hb, Wt, 9, x, x);

    mlstm(1);

    fc_kernel<<<32, 64, 0, stream>>>(x, fcW, fcb, (float*)d_out);
}